// Round 1
// baseline (424.710 us; speedup 1.0000x reference)
//
#include <hip/hip_runtime.h>
#include <hip/hip_bf16.h>

#define KC 32
#define BM 128
#define BN 128
#define LSTRIDE 132  // padded LDS row stride (floats): 16B-aligned rows, conflict-light

// ---------------- kernel 1: q[m] = (counts[m] > 0) ? 1/||p_m|| : 0 ----------------
__global__ __launch_bounds__(64) void proto_qnorm_kernel(
    const float* __restrict__ P, const int* __restrict__ counts,
    float* __restrict__ q, int M, int Dd) {
  int m = blockIdx.x;
  int lane = threadIdx.x;
  float s = 0.f;
  for (int k = lane * 4; k < Dd; k += 256) {
    float4 v = *reinterpret_cast<const float4*>(P + (size_t)m * Dd + k);
    s += v.x * v.x + v.y * v.y + v.z * v.z + v.w * v.w;
  }
  for (int off = 32; off > 0; off >>= 1) s += __shfl_xor(s, off, 64);
  if (lane == 0) {
    q[m] = (counts[m] > 0) ? (1.0f / sqrtf(s)) : 0.0f;
  }
}

// ---------------- kernel 2: tiled f32 GEMM + running argmax ----------------
// Block: 256 threads (4 waves as 2x2). Tile: 128 rows x 128 protos, K staged in
// chunks of 32 (transposed in LDS). Each lane owns an 8x8 micro-tile.
__global__ __launch_bounds__(256) void simargmax_kernel(
    const float* __restrict__ E, const float* __restrict__ P,
    const float* __restrict__ q, int* __restrict__ out,
    int N, int M, int Dd) {
  __shared__ float lds[2 * KC * LSTRIDE];
  float* At = lds;
  float* Bt = lds + KC * LSTRIDE;

  const int tid = threadIdx.x;
  const int wave = tid >> 6;
  const int lane = tid & 63;
  const int wr = wave >> 1, wc = wave & 1;
  const int lr = lane >> 3, lc = lane & 7;
  const int r0 = wr * 64 + lr * 8;  // local row base (8 consecutive rows)
  const int c0 = wc * 64 + lc * 8;  // local col base (8 consecutive protos)
  const int blockRow = blockIdx.x * BM;

  float bv[8];
  int bmi[8];
#pragma unroll
  for (int i = 0; i < 8; ++i) { bv[i] = -3.0e38f; bmi[i] = 0; }

  const int nPt = M / BN;
  const int nKc = Dd / KC;

  for (int pt = 0; pt < nPt; ++pt) {
    float acc[8][8];
#pragma unroll
    for (int i = 0; i < 8; ++i)
#pragma unroll
      for (int j = 0; j < 8; ++j) acc[i][j] = 0.f;

    for (int kc = 0; kc < nKc; ++kc) {
      // ---- stage A (128x32) and B (128x32) transposed into LDS ----
#pragma unroll
      for (int it = 0; it < 4; ++it) {
        int jj = it * 256 + tid;      // 0..1023
        int row = jj >> 3;            // 0..127
        int kg = jj & 7;              // which float4 along k
        int kk = kg * 4;
        float4 va = *reinterpret_cast<const float4*>(
            E + (size_t)(blockRow + row) * Dd + kc * KC + kk);
        At[(kk + 0) * LSTRIDE + row] = va.x;
        At[(kk + 1) * LSTRIDE + row] = va.y;
        At[(kk + 2) * LSTRIDE + row] = va.z;
        At[(kk + 3) * LSTRIDE + row] = va.w;
        float4 vb = *reinterpret_cast<const float4*>(
            P + (size_t)(pt * BN + row) * Dd + kc * KC + kk);
        Bt[(kk + 0) * LSTRIDE + row] = vb.x;
        Bt[(kk + 1) * LSTRIDE + row] = vb.y;
        Bt[(kk + 2) * LSTRIDE + row] = vb.z;
        Bt[(kk + 3) * LSTRIDE + row] = vb.w;
      }
      __syncthreads();

      // ---- compute: 8x8 micro-tile per lane ----
#pragma unroll 4
      for (int kk = 0; kk < KC; ++kk) {
        float4 a0 = *reinterpret_cast<const float4*>(&At[kk * LSTRIDE + r0]);
        float4 a1 = *reinterpret_cast<const float4*>(&At[kk * LSTRIDE + r0 + 4]);
        float4 b0 = *reinterpret_cast<const float4*>(&Bt[kk * LSTRIDE + c0]);
        float4 b1 = *reinterpret_cast<const float4*>(&Bt[kk * LSTRIDE + c0 + 4]);
        float a[8] = {a0.x, a0.y, a0.z, a0.w, a1.x, a1.y, a1.z, a1.w};
        float b[8] = {b0.x, b0.y, b0.z, b0.w, b1.x, b1.y, b1.z, b1.w};
#pragma unroll
        for (int i = 0; i < 8; ++i)
#pragma unroll
          for (int j = 0; j < 8; ++j) acc[i][j] = fmaf(a[i], b[j], acc[i][j]);
      }
      __syncthreads();
    }

    // ---- fold this proto-tile into the running argmax ----
    const float* qbase = q + pt * BN + c0;
    float4 q0 = *reinterpret_cast<const float4*>(qbase);
    float4 q1 = *reinterpret_cast<const float4*>(qbase + 4);
    float qv[8] = {q0.x, q0.y, q0.z, q0.w, q1.x, q1.y, q1.z, q1.w};
#pragma unroll
    for (int j = 0; j < 8; ++j) {
      int m = pt * BN + c0 + j;
      float qq = qv[j];
#pragma unroll
      for (int i = 0; i < 8; ++i) {
        float v = (qq > 0.f) ? acc[i][j] * qq : -1.0e30f;
        if (v > bv[i]) { bv[i] = v; bmi[i] = m; }  // strict >: keeps first (lowest m)
      }
    }
  }

  // ---- cross-lane argmax reduction (16 candidates per row) ----
  // reuse LDS (all compute reads finished before the last __syncthreads)
  float* red_val = lds;                                   // [128][16]
  int* red_idx = reinterpret_cast<int*>(lds + BM * 16);   // [128][16]
  const int cand = wc * 8 + lc;
#pragma unroll
  for (int i = 0; i < 8; ++i) {
    red_val[(r0 + i) * 16 + cand] = bv[i];
    red_idx[(r0 + i) * 16 + cand] = bmi[i];
  }
  __syncthreads();
  if (tid < BM) {
    float best = red_val[tid * 16];
    int bidx = red_idx[tid * 16];
    for (int cnd = 1; cnd < 16; ++cnd) {
      float v = red_val[tid * 16 + cnd];
      int m = red_idx[tid * 16 + cnd];
      if (v > best || (v == best && m < bidx)) { best = v; bidx = m; }
    }
    out[blockRow + tid] = bidx;
  }
}

extern "C" void kernel_launch(void* const* d_in, const int* in_sizes, int n_in,
                              void* d_out, int out_size, void* d_ws, size_t ws_size,
                              hipStream_t stream) {
  const float* E = (const float*)d_in[0];
  const float* P = (const float*)d_in[1];
  const int* counts = (const int*)d_in[2];
  const int M = in_sizes[2];            // 1024
  const int Dd = in_sizes[1] / M;       // 256
  const int N = in_sizes[0] / Dd;       // 65536
  float* q = (float*)d_ws;              // M floats of scratch
  int* out = (int*)d_out;

  proto_qnorm_kernel<<<M, 64, 0, stream>>>(P, counts, q, M, Dd);
  simargmax_kernel<<<N / BM, 256, 0, stream>>>(E, P, q, out, N, M, Dd);
}